// Round 11
// baseline (155.931 us; speedup 1.0000x reference)
//
#include <hip/hip_runtime.h>

#define N_NODES 100000
#define N_EDGES 1600000
#define DIM 128
#define NH 4

#define NPB 512                                   // nodes per coarse bucket
#define NB 196                                    // ceil(N_NODES / NPB)
#define CAP 12288                                 // padded bucket capacity (mean 8192)
#define BCHUNK 8192                               // edges per scatter block
#define BEPT 32                                   // BCHUNK / 256
#define NBLK ((N_EDGES + BCHUNK - 1) / BCHUNK)    // 196

typedef __attribute__((ext_vector_type(8))) short bf16x8;
typedef __attribute__((ext_vector_type(4))) float f32x4;
typedef __attribute__((ext_vector_type(8))) unsigned short u16x8;

// ws layout, BYTE offsets:
//   bcur   : [0, 1024)           int[256] absolute bucket cursors (init t*CAP)
//   rowoff : [4096, 404096)      int[100000] packed (csr_lo<<9)|deg
//   csr    : [405504, 6805504)   int[1.6M] src ids, dense, bucketed+sorted by dst
//   wpack  : [6805504, 6871040)  bf16 MFMA-packed Ws|Wn
//   bavg   : [6871040, 6871552)  f32[128]
//   hb     : [6871552, 32471552) bf16 copy of h (25.6MB)
// ebuf (padded buckets, 256*CAP ints = 12.6MB) lives in d_out: dead before gather.
#define B_BCUR   0u
#define B_ROWOFF 4096u
#define B_CSR    405504u
#define B_WPACK  6805504u
#define B_BAVG   6871040u
#define B_HB     6871552u
#define NEED_BF16 32869376ull

// branchless RTNE f32->bf16 (finite inputs; no NaN path)
__device__ inline unsigned short f2bf(float x) {
    union { float f; unsigned u; } v; v.f = x;
    unsigned r = v.u + 0x7fffu + ((v.u >> 16) & 1u);
    return (unsigned short)(r >> 16);
}

// ---------------------------------------------------------------------------
// prep: (BF, all blocks) h -> bf16 copy; (blocks<64) head-averaged
// MFMA-B-frag-packed weights; (block 0) bavg + absolute bucket cursors.
// ---------------------------------------------------------------------------
template <bool BF>
__global__ __launch_bounds__(256) void prep_kernel(
    const float* __restrict__ h, unsigned short* __restrict__ hb,
    const float* __restrict__ Ws, const float* __restrict__ Wn,
    const float* __restrict__ b, unsigned short* __restrict__ wpack,
    float* __restrict__ bavg, int* __restrict__ bcur) {
    const int t = threadIdx.x;
    if (blockIdx.x == 0) bcur[t] = t * CAP;
    int i = blockIdx.x * 256 + t;
    if (i < DIM * DIM) {
        float s = 0.f, n = 0.f;
#pragma unroll
        for (int hh = 0; hh < NH; ++hh) {
            s += Ws[hh * DIM * DIM + i];
            n += Wn[hh * DIM * DIM + i];
        }
        s *= 0.25f; n *= 0.25f;
        int k = i >> 7, o = i & 127;
        int nt = o >> 4, lanelo = o & 15;
        int ks = k >> 5, lanehi = (k & 31) >> 3, e = k & 7;
        int pos = (((nt * 4 + ks) * 64) + lanehi * 16 + lanelo) * 8 + e;
        wpack[pos] = f2bf(s);
        wpack[16384 + pos] = f2bf(n);
    }
    if (i < DIM) {
        float bb = 0.f;
#pragma unroll
        for (int hh = 0; hh < NH; ++hh) bb += b[hh * DIM + i];
        bavg[i] = 0.25f * bb;
    }
    if (BF) {  // 8 elems/thread bf16 conversion
        const float4* p = reinterpret_cast<const float4*>(h) + (size_t)i * 2;
        float4 a = p[0], c = p[1];
        u16x8 r;
        r[0] = f2bf(a.x); r[1] = f2bf(a.y); r[2] = f2bf(a.z); r[3] = f2bf(a.w);
        r[4] = f2bf(c.x); r[5] = f2bf(c.y); r[6] = f2bf(c.z); r[7] = f2bf(c.w);
        reinterpret_cast<u16x8*>(hb)[i] = r;
    }
}

// ---------------------------------------------------------------------------
// single-pass bucket scatter (absolute cursors; ~32-edge cacheline runs)
// ---------------------------------------------------------------------------
__global__ __launch_bounds__(256) void bucket_scatter_kernel(const int* __restrict__ src,
                                                             const int* __restrict__ dst,
                                                             int* __restrict__ bcur,
                                                             int* __restrict__ ebuf) {
    __shared__ int stage[BCHUNK];
    __shared__ unsigned char bkt[BCHUNK];
    __shared__ int lc[256], lbase[256], lpos[256];
    int t = threadIdx.x;
    lc[t] = 0;
    lpos[t] = 0;
    __syncthreads();
    int e0 = blockIdx.x * BCHUNK;
#pragma unroll 4
    for (int j = 0; j < BEPT; ++j) {
        int e = e0 + j * 256 + t;
        if (e < N_EDGES) {
            int d = dst[e];
            stage[j * 256 + t] = (src[e] << 9) | (d & (NPB - 1));
            bkt[j * 256 + t] = (unsigned char)(d >> 9);
            atomicAdd(&lc[d >> 9], 1);
        }
    }
    __syncthreads();
    if (lc[t]) lbase[t] = atomicAdd(&bcur[t], lc[t]);
    __syncthreads();
#pragma unroll 4
    for (int j = 0; j < BEPT; ++j) {
        int e = e0 + j * 256 + t;
        if (e < N_EDGES) {
            int bb = bkt[j * 256 + t];
            int o = atomicAdd(&lpos[bb], 1);
            ebuf[lbase[bb] + o] = stage[j * 256 + t];
        }
    }
}

// ---------------------------------------------------------------------------
// one block per bucket: internal 256-bucket scan, local 512-slot hist + scan
// -> packed rowoff ((lo<<9)|deg), then scatter src into the dense csr window.
// ---------------------------------------------------------------------------
__global__ __launch_bounds__(256) void csr_build_kernel(const int* __restrict__ bcur,
                                                        const int* __restrict__ ebuf,
                                                        int* __restrict__ rowoff,
                                                        int* __restrict__ csr) {
    __shared__ int hh[NPB], off[NPB], cur[NPB], ss[256];
    int b = blockIdx.x, t = threadIdx.x;
    int cnt = bcur[b] - b * CAP;
    int ibase = b * CAP;
    // internal exclusive scan of all 256 bucket counts -> obase
    ss[t] = bcur[t] - t * CAP;
    __syncthreads();
    for (int o = 1; o < 256; o <<= 1) {
        int add = (t >= o) ? ss[t - o] : 0;
        __syncthreads();
        ss[t] += add;
        __syncthreads();
    }
    int obase = ss[b] - cnt;
    hh[t] = 0; hh[t + 256] = 0;
    cur[t] = 0; cur[t + 256] = 0;
    __syncthreads();
    for (int i = t; i < cnt; i += 256) atomicAdd(&hh[ebuf[ibase + i] & (NPB - 1)], 1);
    __syncthreads();
    int e0 = hh[2 * t], e1 = hh[2 * t + 1];
    ss[t] = e0 + e1;
    __syncthreads();
    for (int o = 1; o < 256; o <<= 1) {
        int add = (t >= o) ? ss[t - o] : 0;
        __syncthreads();
        ss[t] += add;
        __syncthreads();
    }
    int ex = ss[t] - (e0 + e1);
    off[2 * t] = ex;
    off[2 * t + 1] = ex + e0;
    __syncthreads();
    int n0 = b * NPB;
#pragma unroll
    for (int k = 0; k < 2; ++k) {
        int s2 = 2 * t + k;
        int n = n0 + s2;
        int dgv = (k == 0) ? e0 : e1;
        if (n < N_NODES) rowoff[n] = ((obase + off[s2]) << 9) | min(dgv, 511);
    }
    for (int i = t; i < cnt; i += 256) {
        int p = ebuf[ibase + i];
        int nl = p & (NPB - 1);
        int o = atomicAdd(&cur[nl], 1);
        csr[obase + off[nl] + o] = p >> 9;
    }
}

// ---------------------------------------------------------------------------
// FUSED gather + GEMM, occupancy-preserving geometry:
// block = 1024 threads = 16 waves; each wave gathers EXACTLY ONE node (same
// per-node TLP as the split kernel: 4 edge-slots x 16 lanes x 16B, 2-deep ILP),
// rounds the mean to bf16 (same rounding point -> bit-identical output), puts
// it in LDS; one barrier; waves 0..7 each compute one 16-col MFMA tile for the
// block's 16 nodes. 100000 = 6250 x 16 exactly -> no tail handling.
// ---------------------------------------------------------------------------
template <bool BF>
__global__ __launch_bounds__(1024, 8) void gather_gemm_kernel(
    const float* __restrict__ h, const unsigned short* __restrict__ hb,
    const int* __restrict__ rowoff, const int* __restrict__ csr,
    float* __restrict__ out, const unsigned short* __restrict__ wpack,
    const float* __restrict__ bavg) {
    __shared__ unsigned short hnl[16][DIM + 8];  // +8 pad -> 2-way ds_read (free)
    const int lane = threadIdx.x & 63;
    const int w = threadIdx.x >> 6;       // wave id 0..15
    const int nb = blockIdx.x * 16;       // block's node base

    // ---- Phase 1: this wave gathers node nb+w ----
    {
        const int node = nb + w;
        const int g = lane >> 4;   // edge slot
        const int c = lane & 15;   // 16B chunk within row
        const int pw = rowoff[node];
        const int lo = pw >> 9, dg = pw & 511, hi = lo + dg;
        float a0 = 0.f, a1 = 0.f, a2 = 0.f, a3 = 0.f;
        float a4 = 0.f, a5 = 0.f, a6 = 0.f, a7 = 0.f;
        if (BF) {
            int k = lo + g;
            for (; k + 4 < hi; k += 8) {  // 2 independent row loads in flight
                int s0 = csr[k], s1 = csr[k + 4];
                uint4 v = *reinterpret_cast<const uint4*>(hb + (size_t)s0 * DIM + c * 8);
                uint4 u = *reinterpret_cast<const uint4*>(hb + (size_t)s1 * DIM + c * 8);
                a0 += __uint_as_float(v.x << 16) + __uint_as_float(u.x << 16);
                a1 += __uint_as_float(v.x & 0xffff0000u) + __uint_as_float(u.x & 0xffff0000u);
                a2 += __uint_as_float(v.y << 16) + __uint_as_float(u.y << 16);
                a3 += __uint_as_float(v.y & 0xffff0000u) + __uint_as_float(u.y & 0xffff0000u);
                a4 += __uint_as_float(v.z << 16) + __uint_as_float(u.z << 16);
                a5 += __uint_as_float(v.z & 0xffff0000u) + __uint_as_float(u.z & 0xffff0000u);
                a6 += __uint_as_float(v.w << 16) + __uint_as_float(u.w << 16);
                a7 += __uint_as_float(v.w & 0xffff0000u) + __uint_as_float(u.w & 0xffff0000u);
            }
            if (k < hi) {
                uint4 v = *reinterpret_cast<const uint4*>(hb + (size_t)csr[k] * DIM + c * 8);
                a0 += __uint_as_float(v.x << 16);
                a1 += __uint_as_float(v.x & 0xffff0000u);
                a2 += __uint_as_float(v.y << 16);
                a3 += __uint_as_float(v.y & 0xffff0000u);
                a4 += __uint_as_float(v.z << 16);
                a5 += __uint_as_float(v.z & 0xffff0000u);
                a6 += __uint_as_float(v.w << 16);
                a7 += __uint_as_float(v.w & 0xffff0000u);
            }
        } else {
            for (int k = lo + g; k < hi; k += 4) {
                const float4* p = reinterpret_cast<const float4*>(h + (size_t)csr[k] * DIM + c * 8);
                float4 x = p[0], y = p[1];
                a0 += x.x; a1 += x.y; a2 += x.z; a3 += x.w;
                a4 += y.x; a5 += y.y; a6 += y.z; a7 += y.w;
            }
        }
        a0 += __shfl_xor(a0, 16, 64); a0 += __shfl_xor(a0, 32, 64);
        a1 += __shfl_xor(a1, 16, 64); a1 += __shfl_xor(a1, 32, 64);
        a2 += __shfl_xor(a2, 16, 64); a2 += __shfl_xor(a2, 32, 64);
        a3 += __shfl_xor(a3, 16, 64); a3 += __shfl_xor(a3, 32, 64);
        a4 += __shfl_xor(a4, 16, 64); a4 += __shfl_xor(a4, 32, 64);
        a5 += __shfl_xor(a5, 16, 64); a5 += __shfl_xor(a5, 32, 64);
        a6 += __shfl_xor(a6, 16, 64); a6 += __shfl_xor(a6, 32, 64);
        a7 += __shfl_xor(a7, 16, 64); a7 += __shfl_xor(a7, 32, 64);
        if (g == 0) {
            float inv = 1.0f / (float)max(dg, 1);
            u16x8 rr;
            rr[0] = f2bf(a0 * inv); rr[1] = f2bf(a1 * inv);
            rr[2] = f2bf(a2 * inv); rr[3] = f2bf(a3 * inv);
            rr[4] = f2bf(a4 * inv); rr[5] = f2bf(a5 * inv);
            rr[6] = f2bf(a6 * inv); rr[7] = f2bf(a7 * inv);
            *reinterpret_cast<u16x8*>(&hnl[w][c * 8]) = rr;
        }
    }
    __syncthreads();

    // ---- Phase 2: waves 0..7 each do one 16-col tile of the 16-node GEMM ----
    if (w < 8) {
        const int nt = w;
        const int khi = lane >> 4;
        const int rowc = nb + (lane & 15);
        f32x4 acc = {};
        const unsigned short* wn_p = wpack + 16384;
#pragma unroll
        for (int ks = 0; ks < 4; ++ks) {
            const int k0 = ks * 32 + khi * 8;
            bf16x8 ha;
            if (BF) {
                ha = *reinterpret_cast<const bf16x8*>(hb + (size_t)rowc * DIM + k0);
            } else {
                const float4* hp = reinterpret_cast<const float4*>(h + (size_t)rowc * DIM + k0);
                float4 x = hp[0], y = hp[1];
                ha[0] = (short)f2bf(x.x); ha[1] = (short)f2bf(x.y);
                ha[2] = (short)f2bf(x.z); ha[3] = (short)f2bf(x.w);
                ha[4] = (short)f2bf(y.x); ha[5] = (short)f2bf(y.y);
                ha[6] = (short)f2bf(y.z); ha[7] = (short)f2bf(y.w);
            }
            bf16x8 na = *reinterpret_cast<const bf16x8*>(&hnl[lane & 15][k0]);
            bf16x8 bs = *reinterpret_cast<const bf16x8*>(wpack + (size_t)(((nt * 4 + ks) * 64 + lane) * 8));
            acc = __builtin_amdgcn_mfma_f32_16x16x32_bf16(ha, bs, acc, 0, 0, 0);
            bf16x8 bn = *reinterpret_cast<const bf16x8*>(wn_p + (size_t)(((nt * 4 + ks) * 64 + lane) * 8));
            acc = __builtin_amdgcn_mfma_f32_16x16x32_bf16(na, bn, acc, 0, 0, 0);
        }
        // C/D layout (verified m89): col = lane&15, row = (lane>>4)*4 + reg
        const int o = nt * 16 + (lane & 15);
        const float bb = bavg[o];
        const int r0 = nb + khi * 4;
#pragma unroll
        for (int r = 0; r < 4; ++r)
            out[(size_t)(r0 + r) * DIM + o] = acc[r] + bb;
    }
}

extern "C" void kernel_launch(void* const* d_in, const int* in_sizes, int n_in,
                              void* d_out, int out_size, void* d_ws, size_t ws_size,
                              hipStream_t stream) {
    const float* h  = (const float*)d_in[0];
    const int* src  = (const int*)d_in[1];
    const int* dst  = (const int*)d_in[2];
    const float* Ws = (const float*)d_in[3];
    const float* Wn = (const float*)d_in[4];
    const float* b  = (const float*)d_in[5];
    float* out = (float*)d_out;

    char* ws = (char*)d_ws;
    int* bcur   = (int*)(ws + B_BCUR);
    int* rowoff = (int*)(ws + B_ROWOFF);
    int* csr    = (int*)(ws + B_CSR);
    unsigned short* wpack = (unsigned short*)(ws + B_WPACK);
    float* bavg = (float*)(ws + B_BAVG);
    unsigned short* hb = (unsigned short*)(ws + B_HB);
    int* ebuf   = (int*)d_out;  // padded buckets (12.6MB); dead before gather

    const bool bf = (ws_size >= NEED_BF16);

    if (bf)
        prep_kernel<true><<<(N_NODES * DIM / 8) / 256, 256, 0, stream>>>(h, hb, Ws, Wn, b, wpack, bavg, bcur);
    else
        prep_kernel<false><<<64, 256, 0, stream>>>(h, hb, Ws, Wn, b, wpack, bavg, bcur);
    bucket_scatter_kernel<<<NBLK, 256, 0, stream>>>(src, dst, bcur, ebuf);
    csr_build_kernel<<<NB, 256, 0, stream>>>(bcur, ebuf, rowoff, csr);
    const int fused_blocks = N_NODES / 16;  // 6250, exact
    if (bf)
        gather_gemm_kernel<true><<<fused_blocks, 1024, 0, stream>>>(h, hb, rowoff, csr, out, wpack, bavg);
    else
        gather_gemm_kernel<false><<<fused_blocks, 1024, 0, stream>>>(h, hb, rowoff, csr, out, wpack, bavg);
}